// Round 7
// baseline (299.765 us; speedup 1.0000x reference)
//
#include <hip/hip_runtime.h>
#include <stdint.h>

#define DI static __device__ __forceinline__

constexpr int NTOK = 9216;   // 96*96 feat tokens per batch
constexpr float ATT_SCALE = 0.125f;

typedef short bf16x8 __attribute__((ext_vector_type(8)));
typedef float f32x4  __attribute__((ext_vector_type(4)));

DI f32x4 mfma16(bf16x8 a, bf16x8 b, f32x4 c) {
  return __builtin_amdgcn_mfma_f32_16x16x32_bf16(a, b, c, 0, 0, 0);
}

DI float b2f(uint16_t u) { union { uint32_t i; float f; } v; v.i = ((uint32_t)u) << 16; return v.f; }
DI uint16_t f2b(float f) {
  union { float f; uint32_t i; } v; v.f = f;
  uint32_t r = (v.i + 0x7fffu + ((v.i >> 16) & 1u)) >> 16;
  return (uint16_t)r;
}

// ---- dtype-generic element access (DT: 1 = bf16 storage, 0 = fp32 storage) --
template<int DT> DI float ld1(const void* p, size_t off) {
  if constexpr (DT) return b2f(((const uint16_t*)p)[off]);
  else              return ((const float*)p)[off];
}
template<int DT> DI void st1(void* p, size_t off, float v) {
  if constexpr (DT) ((uint16_t*)p)[off] = f2b(v);
  else              ((float*)p)[off] = v;
}

// ---------------------------------------------------------------------------
// Inline per-block dtype flag (low halves of Wfqv words 0..255; bf16-
// plausible magnitude count >= 128). Requires 256-thread blocks.
// ---------------------------------------------------------------------------
DI int block_flag256(const uint32_t* __restrict__ w) {
  const float b = b2f((uint16_t)(w[threadIdx.x & 255] & 0xffffu));
  const float ab = fabsf(b);
  return (__syncthreads_count((ab > 1e-4f && ab < 0.5f) ? 1 : 0) >= 128) ? 1 : 0;
}

// ---------------------------------------------------------------------------
// K1 merged: prep_w (blocks 0..767) || map_qv (blocks 768..2815).
// ---------------------------------------------------------------------------
template<int DT>
DI void prep_w_dev(int r, const void* __restrict__ Wfqv, const void* __restrict__ Wfo,
                   uint16_t* __restrict__ WqvP, uint16_t* __restrict__ WfoP)
{
  const int c = threadIdx.x;
  if (r < 512) {
    const int sel = r >> 8, within = r & 255;
    const int h = within >> 6, d = within & 63;
    const int src = sel * 256 + d * 4 + h;
    WqvP[(size_t)r * 256 + c] = f2b(ld1<DT>(Wfqv, (size_t)src * 256 + c));
  } else {
    const int ro = r - 512;
    WfoP[(size_t)ro * 256 + c] =
        f2b(ld1<DT>(Wfo, (size_t)ro * 256 + (c & 63) * 4 + (c >> 6)));
  }
}

template<int DT>
DI void map_qv_dev(int o, int bb, const void* __restrict__ Wqv,
                   const void* __restrict__ smap,
                   uint16_t* __restrict__ MQ, uint16_t* __restrict__ MVT)
{
  const int m = threadIdx.x;
  float acc = 0.f;
  #pragma unroll 8
  for (int c = 0; c < 256; ++c)
    acc += ld1<DT>(Wqv, (size_t)o * 256 + c) *
           ld1<DT>(smap, (size_t)bb * 65536 + (size_t)c * 256 + m);
  const int oc = o & 255;
  const int h = oc & 3, d = oc >> 2;
  if (o < 256) MQ[(((size_t)bb * 4 + h) * 256 + m) * 64 + d] = f2b(acc);
  else         MVT[(((size_t)bb * 4 + h) * 64 + d) * 256 + m] = f2b(acc);
}

__global__ __launch_bounds__(256) void prep_map_k(
    const void* Wfqv, const void* Wfo, const void* Wmqv, const void* smap,
    uint16_t* WqvP, uint16_t* WfoP, uint16_t* MQ, uint16_t* MVT)
{
  const int fl = block_flag256((const uint32_t*)Wfqv);
  const int bid = blockIdx.x;
  if (bid < 768) {
    if (fl) prep_w_dev<1>(bid, Wfqv, Wfo, WqvP, WfoP);
    else    prep_w_dev<0>(bid, Wfqv, Wfo, WqvP, WfoP);
  } else {
    const int idx = bid - 768;
    if (fl) map_qv_dev<1>(idx & 511, idx >> 9, Wmqv, smap, MQ, MVT);
    else    map_qv_dev<0>(idx & 511, idx >> 9, Wmqv, smap, MQ, MVT);
  }
}

// ---------------------------------------------------------------------------
// GEMM0 (QV projection), MFMA. Round-7: 32-token blocks, grid (288, 4).
// acc halves to 64 AGPR/wave (was 128 -> 2 waves/SIMD cap); LDS 17.9 KB;
// 1152 blocks. Wave w = head w; feat fetched exactly once; X tile staged
// transposed once; barrier-free k-loop.
// ---------------------------------------------------------------------------
constexpr int P0 = 280;   // gemm0 LDS token-row pitch (elems)

template<int DT>
DI void gemm0_body(uint16_t* Xs, const uint16_t* __restrict__ WqvP,
                   const void* __restrict__ X,
                   uint16_t* __restrict__ FQ, uint16_t* __restrict__ FVt)
{
  const int tid = threadIdx.x;
  const int w = tid >> 6, lane = tid & 63;
  const int l = lane & 15, quad = lane >> 4;
  const int n0 = blockIdx.x * 32;
  const int bb = blockIdx.y;
  const size_t bh = (size_t)bb * 4 + w;    // wave w handles head w

  // ---- stage X[256k][32n] -> Xs[n][k] bf16: thread owns rows nb,nb+1,
  // k-octet kg*8 per pass; 8 coalesced loads -> 2x ds_write_b128.
  {
    const int nb = (tid & 15) * 2;
    const int kg = tid >> 4;             // 0..15
    #pragma unroll
    for (int pass = 0; pass < 2; ++pass) {
      const int k0 = pass * 128 + kg * 8;
      union { uint16_t h[8]; uint4 u; } pk0, pk1;
      #pragma unroll
      for (int j = 0; j < 8; ++j) {
        const size_t g = ((size_t)bb * 256 + k0 + j) * NTOK + n0 + nb;
        if constexpr (DT) {
          const uint32_t v = *(const uint32_t*)((const uint16_t*)X + g);
          pk0.h[j] = (uint16_t)(v & 0xffffu);
          pk1.h[j] = (uint16_t)(v >> 16);
        } else {
          const float2 v = *(const float2*)((const float*)X + g);
          pk0.h[j] = f2b(v.x);
          pk1.h[j] = f2b(v.y);
        }
      }
      *(uint4*)(Xs + (size_t)(nb + 0) * P0 + k0) = pk0.u;
      *(uint4*)(Xs + (size_t)(nb + 1) * P0 + k0) = pk1.u;
    }
  }
  __syncthreads();

  f32x4 acc[2][4][2];   // [sel Q/V][mt][nt] = 64 AGPR
  #pragma unroll
  for (int s = 0; s < 2; ++s)
    #pragma unroll
    for (int a = 0; a < 4; ++a)
      #pragma unroll
      for (int b = 0; b < 2; ++b) { acc[s][a][b].x = 0.f; acc[s][a][b].y = 0.f; acc[s][a][b].z = 0.f; acc[s][a][b].w = 0.f; }

  for (int ks = 0; ks < 8; ++ks) {
    bf16x8 bv[2];
    #pragma unroll
    for (int nt = 0; nt < 2; ++nt)
      bv[nt] = *(const bf16x8*)(Xs + (size_t)(nt * 16 + l) * P0 + ks * 32 + quad * 8);
    #pragma unroll
    for (int s = 0; s < 2; ++s) {
      bf16x8 af[4];
      #pragma unroll
      for (int mt = 0; mt < 4; ++mt) {
        const int arow = s * 256 + w * 64 + mt * 16 + l;
        af[mt] = *(const bf16x8*)(WqvP + (size_t)arow * 256 + ks * 32 + quad * 8);
      }
      #pragma unroll
      for (int nt = 0; nt < 2; ++nt)
        #pragma unroll
        for (int mt = 0; mt < 4; ++mt)
          acc[s][mt][nt] = mfma16(af[mt], bv[nt], acc[s][mt][nt]);
    }
  }
  const int itile = blockIdx.x;            // n0/32
  #pragma unroll
  for (int mt = 0; mt < 4; ++mt)
    #pragma unroll
    for (int nt = 0; nt < 2; ++nt) {
      const int n = n0 + nt * 16 + l;
      {  // Q part
        union { uint16_t h[4]; uint2 u; } pk;
        #pragma unroll
        for (int r = 0; r < 4; ++r) pk.h[r] = f2b(acc[0][mt][nt][r]);
        *(uint2*)(FQ + (bh * NTOK + n) * 64 + mt * 16 + quad * 4) = pk.u;
      }
      {  // V part (tiled layout)
        const int io = n & 31;
        #pragma unroll
        for (int r = 0; r < 4; ++r)
          FVt[(((size_t)bh * 288 + itile) * 64 + mt * 16 + quad * 4 + r) * 32 + io] =
              f2b(acc[1][mt][nt][r]);
      }
    }
}
__global__ __launch_bounds__(256, 3) void gemm0_mfma(
    const uint16_t* WqvP, const void* X, uint16_t* FQ, uint16_t* FVt,
    const void* Wfqv)
{
  __shared__ __align__(16) uint16_t Xs[32 * P0];
  const int fl = block_flag256((const uint32_t*)Wfqv);
  if (fl) gemm0_body<1>(Xs, WqvP, X, FQ, FVt);
  else    gemm0_body<0>(Xs, WqvP, X, FQ, FVt);
}

// ---------------------------------------------------------------------------
// Fused bidirectional attention, MFMA 16x16x32 bf16. Grid (48, 16).
// Hot loop FROZEN at the R2/R5-measured-best configuration. Round-7:
//  - NGRP 36->48 (TPB=6): 768 blocks = exactly 3/CU (the per-CU cap), was
//    576 = 2.25/CU grid-limited at 21% occupancy.
//  - P pitch 64: each j-row is one aligned, fully-written 128-B line ->
//    no RFO/straddle (R6 residual: WRITE +30 MB, FETCH +19 MB). csum moved
//    to separate CS array.
// ---------------------------------------------------------------------------
constexpr int PJ = 280;  // E[i][j] row pitch (560B rows, 16B-aligned)
constexpr int PI = 40;   // ET[j][i] row pitch (80B rows, 16B-aligned)
constexpr int PO = 72;   // Osh row pitch (144 B: 16B-aligned, bank-spread)
constexpr int NGRP = 48; // partial groups (= blocks) per bh
constexpr int TPB = 6;   // i-tiles (of 32 tokens) per block = 288/NGRP

__global__ __launch_bounds__(256, 3) void attn_mfma(
    const uint16_t* __restrict__ FQ, const uint16_t* __restrict__ FVt,
    const uint16_t* __restrict__ MQ, const uint16_t* __restrict__ MVT,
    uint16_t* __restrict__ FO, uint16_t* __restrict__ P,
    uint16_t* __restrict__ CSp)
{
  __shared__ __align__(16) uint16_t Esh[32 * PJ];    // [i][j]
  __shared__ __align__(16) uint16_t ETsh[256 * PI];  // [j][i]
  __shared__ __align__(16) uint16_t Osh[32 * PO];    // [i][d] out-staging
  __shared__ float RS[4][32];
  const int tid = threadIdx.x;
  const int w = tid >> 6;
  const int lane = tid & 63;
  const int l = lane & 15, quad = lane >> 4;
  const int blk = blockIdx.x, bh = blockIdx.y;
  const uint16_t* FQh  = FQ  + (size_t)bh * NTOK * 64;
  const uint16_t* FVth = FVt + (size_t)bh * 288 * 64 * 32;
  const uint16_t* MQh  = MQ  + (size_t)bh * 256 * 64;
  const uint16_t* MVTh = MVT + (size_t)bh * 64 * 256;
  uint16_t* FOh = FO + (size_t)bh * NTOK * 64;

  // ---- hoisted loop-invariant operand fragments ----
  bf16x8 kb[4][2];   // MQ: wave w's 64 map-tokens, both k-halves
  #pragma unroll
  for (int jt = 0; jt < 4; ++jt) {
    const int j = w * 64 + jt * 16 + l;
    kb[jt][0] = *(const bf16x8*)(MQh + (size_t)j * 64 + quad * 8);
    kb[jt][1] = *(const bf16x8*)(MQh + (size_t)j * 64 + 32 + quad * 8);
  }
  bf16x8 avr[8];     // MVT: wave w's 16 d-rows, all 8 k-slices
  #pragma unroll
  for (int ks = 0; ks < 8; ++ks)
    avr[ks] = *(const bf16x8*)(MVTh + (size_t)(w * 16 + l) * 256 + ks * 32 + quad * 8);

  f32x4 numacc[4][4];
  #pragma unroll
  for (int a = 0; a < 4; ++a)
    #pragma unroll
    for (int b = 0; b < 4; ++b) { numacc[a][b].x = 0.f; numacc[a][b].y = 0.f; numacc[a][b].z = 0.f; numacc[a][b].w = 0.f; }
  float csum[4] = {0.f, 0.f, 0.f, 0.f};

  for (int t = 0; t < TPB; ++t) {
    const int it = blk * TPB + t;
    const int i0 = it * 32;

    // ---- QK phase: e_ij into Esh [i][j] and ETsh [j][i]
    bf16x8 qa[2][2];
    #pragma unroll
    for (int mt = 0; mt < 2; ++mt)
      #pragma unroll
      for (int kbi = 0; kbi < 2; ++kbi)
        qa[mt][kbi] = *(const bf16x8*)(FQh + (size_t)(i0 + mt * 16 + l) * 64 + kbi * 32 + quad * 8);

    float rsum[2][4] = {{0.f,0.f,0.f,0.f},{0.f,0.f,0.f,0.f}};
    #pragma unroll
    for (int jt = 0; jt < 4; ++jt) {
      const int j0 = w * 64 + jt * 16;
      #pragma unroll
      for (int mt = 0; mt < 2; ++mt) {
        f32x4 acc = {0.f, 0.f, 0.f, 0.f};
        acc = mfma16(qa[mt][0], kb[jt][0], acc);
        acc = mfma16(qa[mt][1], kb[jt][1], acc);
        union { uint16_t h[4]; uint2 u; } pk;
        #pragma unroll
        for (int r = 0; r < 4; ++r) {
          const float e = __expf(acc[r] * ATT_SCALE);
          rsum[mt][r] += e;
          csum[jt] += e;
          pk.h[r] = f2b(e);
          Esh[(mt * 16 + quad * 4 + r) * PJ + j0 + l] = pk.h[r];
        }
        *(uint2*)(ETsh + (size_t)(j0 + l) * PI + mt * 16 + quad * 4) = pk.u;
      }
    }
    #pragma unroll
    for (int mt = 0; mt < 2; ++mt)
      #pragma unroll
      for (int r = 0; r < 4; ++r) {
        float v = rsum[mt][r];
        v += __shfl_xor(v, 1); v += __shfl_xor(v, 2);
        v += __shfl_xor(v, 4); v += __shfl_xor(v, 8);
        if (l == 0) RS[w][mt * 16 + quad * 4 + r] = v;
      }
    __syncthreads();

    // ---- issue column-phase FVt loads; row phase below covers their latency
    bf16x8 av[4];
    #pragma unroll
    for (int mt = 0; mt < 4; ++mt)
      av[mt] = *(const bf16x8*)(FVth + ((size_t)it * 64 + mt * 16 + l) * 32 + quad * 8);

    // ---- row phase: feat_o^T[d][i] = MVT x E^T, normalized -> Osh
    {
      float rinv[2];
      #pragma unroll
      for (int nt = 0; nt < 2; ++nt) {
        const int i_ = nt * 16 + l;
        rinv[nt] = 1.f / (RS[0][i_] + RS[1][i_] + RS[2][i_] + RS[3][i_]);
      }
      f32x4 oacc[2];
      oacc[0].x=0.f;oacc[0].y=0.f;oacc[0].z=0.f;oacc[0].w=0.f;
      oacc[1]=oacc[0];
      #pragma unroll
      for (int ks = 0; ks < 8; ++ks) {
        #pragma unroll
        for (int nt = 0; nt < 2; ++nt) {
          const bf16x8 bv = *(const bf16x8*)(Esh + (size_t)(nt * 16 + l) * PJ + ks * 32 + quad * 8);
          oacc[nt] = mfma16(avr[ks], bv, oacc[nt]);
        }
      }
      #pragma unroll
      for (int nt = 0; nt < 2; ++nt) {
        union { uint16_t h[4]; uint2 u; } pk;
        #pragma unroll
        for (int r = 0; r < 4; ++r) pk.h[r] = f2b(oacc[nt][r] * rinv[nt]);
        *(uint2*)(Osh + (nt * 16 + l) * PO + w * 16 + quad * 4) = pk.u;
      }
    }

    // ---- column phase: NUM^T[d][j] += FVt-tile x E (regs across tiles)
    #pragma unroll
    for (int mt = 0; mt < 4; ++mt) {
      #pragma unroll
      for (int nt2 = 0; nt2 < 4; ++nt2) {
        const bf16x8 bv = *(const bf16x8*)(ETsh + (size_t)(w * 64 + nt2 * 16 + l) * PI + quad * 8);
        numacc[mt][nt2] = mfma16(av[mt], bv, numacc[mt][nt2]);
      }
    }
    __syncthreads();

    // ---- FO write: full 128-B line per token (8 thr x uint4)
    {
      const int ti = tid >> 3, c = tid & 7;
      *(uint4*)(FOh + (size_t)(i0 + ti) * 64 + c * 8) =
          *(const uint4*)(Osh + ti * PO + c * 8);
    }
  }

  // ---- flush partials: P[j][64d] rows are exactly one 128-B line each,
  // fully written by this wave's 4 uint2 stores -> no RFO.
  uint16_t* Pb = P + ((size_t)bh * NGRP + blk) * 256 * 64;
  #pragma unroll
  for (int mt = 0; mt < 4; ++mt)
    #pragma unroll
    for (int nt2 = 0; nt2 < 4; ++nt2) {
      const int j = w * 64 + nt2 * 16 + l;
      union { uint16_t h[4]; uint2 u; } pk;
      #pragma unroll
      for (int r = 0; r < 4; ++r) pk.h[r] = f2b(numacc[mt][nt2][r]);
      *(uint2*)(Pb + (size_t)j * 64 + mt * 16 + quad * 4) = pk.u;
    }
  uint16_t* CSb = CSp + ((size_t)bh * NGRP + blk) * 256;
  #pragma unroll
  for (int jt = 0; jt < 4; ++jt) {
    float v = csum[jt];
    v += __shfl_xor(v, 16); v += __shfl_xor(v, 32);
    if (quad == 0) CSb[w * 64 + jt * 16 + l] = f2b(v);
  }
}

// ---------------------------------------------------------------------------
// Epilogue: gemm1 (feat out proj) and reduce_map (P,CS -> MO), mergeable.
// mode 0: merged (blocks 0..575 gemm1, 576..1599 reduce)
// mode 1: gemm1 only (576 blocks)   mode 2: reduce only (1024 blocks)
// ---------------------------------------------------------------------------
template<int DT>
DI void gemm1_dev(int gidx, const uint16_t* __restrict__ WfoP,
                  const uint16_t* __restrict__ FO, void* __restrict__ out)
{
  const int tid = threadIdx.x;
  const int w = tid >> 6, lane = tid & 63;
  const int l = lane & 15, quad = lane >> 4;
  const int n0 = (gidx % 36) * 256;
  const int o0 = ((gidx / 36) & 3) * 64;
  const int bb = gidx / 144;

  f32x4 acc[4][4];
  #pragma unroll
  for (int a = 0; a < 4; ++a)
    #pragma unroll
    for (int b = 0; b < 4; ++b) { acc[a][b].x = 0.f; acc[a][b].y = 0.f; acc[a][b].z = 0.f; acc[a][b].w = 0.f; }

  #pragma unroll
  for (int ks = 0; ks < 8; ++ks) {
    const int h2 = ks >> 1;
    const int doff = (ks & 1) * 32 + quad * 8;
    bf16x8 af[4];
    #pragma unroll
    for (int mt = 0; mt < 4; ++mt)
      af[mt] = *(const bf16x8*)(WfoP + (size_t)(o0 + mt * 16 + l) * 256 + ks * 32 + quad * 8);
    #pragma unroll
    for (int nt = 0; nt < 4; ++nt) {
      const int n = n0 + w * 64 + nt * 16 + l;
      const bf16x8 bv = *(const bf16x8*)(FO + ((size_t)(bb * 4 + h2) * NTOK + n) * 64 + doff);
      #pragma unroll
      for (int mt = 0; mt < 4; ++mt)
        acc[mt][nt] = mfma16(af[mt], bv, acc[mt][nt]);
    }
  }
  #pragma unroll
  for (int mt = 0; mt < 4; ++mt)
    #pragma unroll
    for (int nt = 0; nt < 4; ++nt) {
      const int n = n0 + w * 64 + nt * 16 + l;
      #pragma unroll
      for (int r = 0; r < 4; ++r)
        st1<DT>(out, ((size_t)bb * 256 + o0 + mt * 16 + quad * 4 + r) * NTOK + n,
                acc[mt][nt][r]);
    }
}

DI void reduce_dev(int bid, const uint16_t* __restrict__ P,
                   const uint16_t* __restrict__ CSp, uint16_t* __restrict__ MO)
{
  const int idx = bid * 256 + threadIdx.x;   // 262144 total over 1024 blocks
  const int d = idx & 63;
  const int j = (idx >> 6) & 255;
  const int bh = idx >> 14;
  const size_t base = (size_t)bh * NGRP * 256 * 64;
  const size_t cb = (size_t)bh * NGRP * 256;
  float num = 0.f, cs = 0.f;
  #pragma unroll 6
  for (int g = 0; g < NGRP; ++g) {
    num += b2f(P[base + ((size_t)g * 256 + j) * 64 + d]);
    cs  += b2f(CSp[cb + (size_t)g * 256 + j]);
  }
  const float v = num / cs;
  const int b = bh >> 2, h = bh & 3;
  MO[((size_t)b * 256 + (d * 4 + h)) * 256 + j] = f2b(v);
}

__global__ __launch_bounds__(256) void epilogue_k(
    const uint16_t* WfoP, const uint16_t* FO, void* out,
    const uint16_t* P, const uint16_t* CSp, uint16_t* MO,
    const void* Wfqv, int mode)
{
  const int bid = blockIdx.x;
  bool do_g1; int gidx;
  if (mode == 0)      { do_g1 = bid < 576; gidx = do_g1 ? bid : bid - 576; }
  else if (mode == 1) { do_g1 = true;  gidx = bid; }
  else                { do_g1 = false; gidx = bid; }
  if (do_g1) {
    const int fl = block_flag256((const uint32_t*)Wfqv);
    if (fl) gemm1_dev<1>(gidx, WfoP, FO, out);
    else    gemm1_dev<0>(gidx, WfoP, FO, out);
  } else {
    reduce_dev(gidx, P, CSp, MO);
  }
}

// ---------------------------------------------------------------------------
// map output projection (tiny)
// ---------------------------------------------------------------------------
template<int DT>
DI void map_out_body(const void* __restrict__ Wmo, const uint16_t* __restrict__ MO,
                     void* __restrict__ out)
{
  const int o = blockIdx.x, bb = blockIdx.y, m = threadIdx.x;
  float acc = 0.f;
  #pragma unroll 8
  for (int c = 0; c < 256; ++c)
    acc += ld1<DT>(Wmo, (size_t)o * 256 + c) *
           b2f(MO[((size_t)bb * 256 + c) * 256 + m]);
  const size_t MAP_OFS = (size_t)4 * 256 * NTOK;
  st1<DT>(out, MAP_OFS + ((size_t)bb * 256 + o) * 256 + m, acc);
}
__global__ __launch_bounds__(256) void map_out_k(
    const void* Wmo, const uint16_t* MO, void* out, const void* Wfqv)
{
  const int fl = block_flag256((const uint32_t*)Wfqv);
  if (fl) map_out_body<1>(Wmo, MO, out);
  else    map_out_body<0>(Wmo, MO, out);
}

extern "C" void kernel_launch(void* const* d_in, const int* in_sizes, int n_in,
                              void* d_out, int out_size, void* d_ws, size_t ws_size,
                              hipStream_t stream) {
  (void)in_sizes; (void)n_in; (void)out_size;
  const void* feat = d_in[0];
  const void* smap = d_in[1];
  const void* Wfqv = d_in[2];
  const void* Wmqv = d_in[3];
  const void* Wfo  = d_in[4];
  const void* Wmo  = d_in[5];
  char* ws = (char*)d_ws;

  const size_t BIG = (size_t)16 * 64 * NTOK * 2;   // 18,874,368 B
  const size_t SML = (size_t)16 * 256 * 64 * 2;    //    524,288 B
  const size_t FQ_OFF  = 0;                         // FO aliases FQ (token-major)
  const size_t FVT_OFF = FQ_OFF + BIG;
  const size_t MQ_OFF  = FVT_OFF + BIG;
  const size_t MVT_OFF = MQ_OFF + SML;
  const size_t MO_OFF  = MVT_OFF + SML;
  const size_t WQP_OFF = MO_OFF + (size_t)4 * 256 * 256 * 2;
  const size_t WFP_OFF = WQP_OFF + (size_t)512 * 256 * 2;
  const size_t CS_OFF  = WFP_OFF + (size_t)256 * 256 * 2;
  const size_t CS_SIZE = (size_t)16 * NGRP * 256 * 2;        //    393,216 B
  const size_t P_OFF   = CS_OFF + CS_SIZE;
  const size_t P_SIZE  = (size_t)16 * NGRP * 256 * 64 * 2;   // 25,165,824 B
  const size_t NEED    = P_OFF + P_SIZE;                      // ~65.7 MB

  uint16_t* FQ   = (uint16_t*)(ws + FQ_OFF);
  uint16_t* FVt  = (uint16_t*)(ws + FVT_OFF);
  uint16_t* MQ   = (uint16_t*)(ws + MQ_OFF);
  uint16_t* MVT  = (uint16_t*)(ws + MVT_OFF);
  uint16_t* MO   = (uint16_t*)(ws + MO_OFF);
  uint16_t* WqvP = (uint16_t*)(ws + WQP_OFF);
  uint16_t* WfoP = (uint16_t*)(ws + WFP_OFF);

  const bool p_in_ws = (ws_size >= NEED);
  // merged path: P,CS in workspace -> reduce_map concurrent with gemm1.
  // fallback: P,CS in d_out (25.6 MB <= 38.8 MB) -> reduce precedes gemm1.
  uint16_t* P   = p_in_ws ? (uint16_t*)(ws + P_OFF) : (uint16_t*)d_out;
  uint16_t* CSp = p_in_ws ? (uint16_t*)(ws + CS_OFF)
                          : (uint16_t*)((char*)d_out + P_SIZE);

  prep_map_k<<<dim3(2816), 256, 0, stream>>>(Wfqv, Wfo, Wmqv, smap,
                                             WqvP, WfoP, MQ, MVT);
  gemm0_mfma<<<dim3(288, 4), 256, 0, stream>>>(WqvP, feat, FQ, FVt, Wfqv);
  attn_mfma<<<dim3(NGRP, 16), 256, 0, stream>>>(FQ, FVt, MQ, MVT, FQ, P, CSp);
  if (p_in_ws) {
    epilogue_k<<<dim3(1600), 256, 0, stream>>>(WfoP, FQ, d_out, P, CSp, MO, Wfqv, 0);
  } else {
    epilogue_k<<<dim3(1024), 256, 0, stream>>>(WfoP, FQ, d_out, P, CSp, MO, Wfqv, 2);
    epilogue_k<<<dim3(576),  256, 0, stream>>>(WfoP, FQ, d_out, P, CSp, MO, Wfqv, 1);
  }
  map_out_k<<<dim3(256, 4), 256, 0, stream>>>(Wmo, MO, d_out, Wfqv);
}

// Round 8
// 289.264 us; speedup vs baseline: 1.0363x; 1.0363x over previous
//
#include <hip/hip_runtime.h>
#include <stdint.h>

#define DI static __device__ __forceinline__

constexpr int NTOK = 9216;   // 96*96 feat tokens per batch
constexpr float ATT_SCALE = 0.125f;

typedef short bf16x8 __attribute__((ext_vector_type(8)));
typedef float f32x4  __attribute__((ext_vector_type(4)));

DI f32x4 mfma16(bf16x8 a, bf16x8 b, f32x4 c) {
  return __builtin_amdgcn_mfma_f32_16x16x32_bf16(a, b, c, 0, 0, 0);
}

DI float b2f(uint16_t u) { union { uint32_t i; float f; } v; v.i = ((uint32_t)u) << 16; return v.f; }
DI uint16_t f2b(float f) {
  union { float f; uint32_t i; } v; v.f = f;
  uint32_t r = (v.i + 0x7fffu + ((v.i >> 16) & 1u)) >> 16;
  return (uint16_t)r;
}

// ---- dtype-generic element access (DT: 1 = bf16 storage, 0 = fp32 storage) --
template<int DT> DI float ld1(const void* p, size_t off) {
  if constexpr (DT) return b2f(((const uint16_t*)p)[off]);
  else              return ((const float*)p)[off];
}
template<int DT> DI void st1(void* p, size_t off, float v) {
  if constexpr (DT) ((uint16_t*)p)[off] = f2b(v);
  else              ((float*)p)[off] = v;
}

// ---------------------------------------------------------------------------
// Inline per-block dtype flag (low halves of Wfqv words 0..255; bf16-
// plausible magnitude count >= 128). Requires 256-thread blocks.
// ---------------------------------------------------------------------------
DI int block_flag256(const uint32_t* __restrict__ w) {
  const float b = b2f((uint16_t)(w[threadIdx.x & 255] & 0xffffu));
  const float ab = fabsf(b);
  return (__syncthreads_count((ab > 1e-4f && ab < 0.5f) ? 1 : 0) >= 128) ? 1 : 0;
}

// ---------------------------------------------------------------------------
// K1 merged: prep_w (blocks 0..767) || map_qv (blocks 768..2815).
// ---------------------------------------------------------------------------
template<int DT>
DI void prep_w_dev(int r, const void* __restrict__ Wfqv, const void* __restrict__ Wfo,
                   uint16_t* __restrict__ WqvP, uint16_t* __restrict__ WfoP)
{
  const int c = threadIdx.x;
  if (r < 512) {
    const int sel = r >> 8, within = r & 255;
    const int h = within >> 6, d = within & 63;
    const int src = sel * 256 + d * 4 + h;
    WqvP[(size_t)r * 256 + c] = f2b(ld1<DT>(Wfqv, (size_t)src * 256 + c));
  } else {
    const int ro = r - 512;
    WfoP[(size_t)ro * 256 + c] =
        f2b(ld1<DT>(Wfo, (size_t)ro * 256 + (c & 63) * 4 + (c >> 6)));
  }
}

template<int DT>
DI void map_qv_dev(int o, int bb, const void* __restrict__ Wqv,
                   const void* __restrict__ smap,
                   uint16_t* __restrict__ MQ, uint16_t* __restrict__ MVT)
{
  const int m = threadIdx.x;
  float acc = 0.f;
  #pragma unroll 8
  for (int c = 0; c < 256; ++c)
    acc += ld1<DT>(Wqv, (size_t)o * 256 + c) *
           ld1<DT>(smap, (size_t)bb * 65536 + (size_t)c * 256 + m);
  const int oc = o & 255;
  const int h = oc & 3, d = oc >> 2;
  if (o < 256) MQ[(((size_t)bb * 4 + h) * 256 + m) * 64 + d] = f2b(acc);
  else         MVT[(((size_t)bb * 4 + h) * 64 + d) * 256 + m] = f2b(acc);
}

__global__ __launch_bounds__(256) void prep_map_k(
    const void* Wfqv, const void* Wfo, const void* Wmqv, const void* smap,
    uint16_t* WqvP, uint16_t* WfoP, uint16_t* MQ, uint16_t* MVT)
{
  const int fl = block_flag256((const uint32_t*)Wfqv);
  const int bid = blockIdx.x;
  if (bid < 768) {
    if (fl) prep_w_dev<1>(bid, Wfqv, Wfo, WqvP, WfoP);
    else    prep_w_dev<0>(bid, Wfqv, Wfo, WqvP, WfoP);
  } else {
    const int idx = bid - 768;
    if (fl) map_qv_dev<1>(idx & 511, idx >> 9, Wmqv, smap, MQ, MVT);
    else    map_qv_dev<0>(idx & 511, idx >> 9, Wmqv, smap, MQ, MVT);
  }
}

// ---------------------------------------------------------------------------
// GEMM0 (QV projection), MFMA. Grid (144 n-slabs, 4 batch), 256 thr.
// REVERTED to the R6 64-token version: R7's 32-token split halved
// A-fragment reuse and doubled weight re-reads (wall-attn 199 -> 214 us).
// Block = 64 tokens x all 512 out-channels (wave w = head w); feat fetched
// once; X tile staged transposed once; barrier-free k-loop.
// ---------------------------------------------------------------------------
constexpr int P0 = 280;   // gemm0 LDS token-row pitch (elems)

template<int DT>
DI void gemm0_body(uint16_t* Xs, const uint16_t* __restrict__ WqvP,
                   const void* __restrict__ X,
                   uint16_t* __restrict__ FQ, uint16_t* __restrict__ FVt)
{
  const int tid = threadIdx.x;
  const int w = tid >> 6, lane = tid & 63;
  const int l = lane & 15, quad = lane >> 4;
  const int n0 = blockIdx.x * 64;
  const int bb = blockIdx.y;
  const size_t bh = (size_t)bb * 4 + w;    // wave w handles head w

  // ---- stage X[256k][64n] -> Xs[n][k] bf16: thread owns rows nb,nb+1,
  // k-octet kg*8 per pass; 8 coalesced loads -> 2x ds_write_b128.
  {
    const int nb = (tid & 31) * 2;
    const int kg = tid >> 5;
    #pragma unroll
    for (int pass = 0; pass < 4; ++pass) {
      const int k0 = pass * 64 + kg * 8;
      union { uint16_t h[8]; uint4 u; } pk0, pk1;
      #pragma unroll
      for (int j = 0; j < 8; ++j) {
        const size_t g = ((size_t)bb * 256 + k0 + j) * NTOK + n0 + nb;
        if constexpr (DT) {
          const uint32_t v = *(const uint32_t*)((const uint16_t*)X + g);
          pk0.h[j] = (uint16_t)(v & 0xffffu);
          pk1.h[j] = (uint16_t)(v >> 16);
        } else {
          const float2 v = *(const float2*)((const float*)X + g);
          pk0.h[j] = f2b(v.x);
          pk1.h[j] = f2b(v.y);
        }
      }
      *(uint4*)(Xs + (size_t)(nb + 0) * P0 + k0) = pk0.u;
      *(uint4*)(Xs + (size_t)(nb + 1) * P0 + k0) = pk1.u;
    }
  }
  __syncthreads();

  f32x4 acc[8][4];
  #pragma unroll
  for (int a = 0; a < 8; ++a)
    #pragma unroll
    for (int b = 0; b < 4; ++b) { acc[a][b].x = 0.f; acc[a][b].y = 0.f; acc[a][b].z = 0.f; acc[a][b].w = 0.f; }

  for (int ks = 0; ks < 8; ++ks) {
    bf16x8 af[8];
    #pragma unroll
    for (int mt = 0; mt < 8; ++mt) {
      const int arow = (mt >> 2) * 256 + w * 64 + (mt & 3) * 16 + l;
      af[mt] = *(const bf16x8*)(WqvP + (size_t)arow * 256 + ks * 32 + quad * 8);
    }
    #pragma unroll
    for (int nt = 0; nt < 4; ++nt) {
      const bf16x8 bv = *(const bf16x8*)(Xs + (size_t)(nt * 16 + l) * P0 + ks * 32 + quad * 8);
      #pragma unroll
      for (int mt = 0; mt < 8; ++mt)
        acc[mt][nt] = mfma16(af[mt], bv, acc[mt][nt]);
    }
  }
  #pragma unroll
  for (int mt = 0; mt < 8; ++mt)
    #pragma unroll
    for (int nt = 0; nt < 4; ++nt) {
      const int n = n0 + nt * 16 + l;
      if (mt < 4) {
        union { uint16_t h[4]; uint2 u; } pk;
        #pragma unroll
        for (int r = 0; r < 4; ++r) pk.h[r] = f2b(acc[mt][nt][r]);
        *(uint2*)(FQ + (bh * NTOK + n) * 64 + mt * 16 + quad * 4) = pk.u;
      } else {
        const int itile = n >> 5, io = n & 31;
        #pragma unroll
        for (int r = 0; r < 4; ++r)
          FVt[(((size_t)bh * 288 + itile) * 64 + (mt - 4) * 16 + quad * 4 + r) * 32 + io] =
              f2b(acc[mt][nt][r]);
      }
    }
}
__global__ __launch_bounds__(256) void gemm0_mfma(
    const uint16_t* WqvP, const void* X, uint16_t* FQ, uint16_t* FVt,
    const void* Wfqv)
{
  __shared__ __align__(16) uint16_t Xs[64 * P0];
  const int fl = block_flag256((const uint32_t*)Wfqv);
  if (fl) gemm0_body<1>(Xs, WqvP, X, FQ, FVt);
  else    gemm0_body<0>(Xs, WqvP, X, FQ, FVt);
}

// ---------------------------------------------------------------------------
// Fused bidirectional attention, MFMA 16x16x32 bf16. Grid (48, 16).
// FROZEN at the R7-measured configuration (86.4 us, occ 29%).
// ---------------------------------------------------------------------------
constexpr int PJ = 280;  // E[i][j] row pitch (560B rows, 16B-aligned)
constexpr int PI = 40;   // ET[j][i] row pitch (80B rows, 16B-aligned)
constexpr int PO = 72;   // Osh row pitch (144 B: 16B-aligned, bank-spread)
constexpr int NGRP = 48; // partial groups (= blocks) per bh
constexpr int TPB = 6;   // i-tiles (of 32 tokens) per block = 288/NGRP

__global__ __launch_bounds__(256, 3) void attn_mfma(
    const uint16_t* __restrict__ FQ, const uint16_t* __restrict__ FVt,
    const uint16_t* __restrict__ MQ, const uint16_t* __restrict__ MVT,
    uint16_t* __restrict__ FO, uint16_t* __restrict__ P,
    uint16_t* __restrict__ CSp)
{
  __shared__ __align__(16) uint16_t Esh[32 * PJ];    // [i][j]
  __shared__ __align__(16) uint16_t ETsh[256 * PI];  // [j][i]
  __shared__ __align__(16) uint16_t Osh[32 * PO];    // [i][d] out-staging
  __shared__ float RS[4][32];
  const int tid = threadIdx.x;
  const int w = tid >> 6;
  const int lane = tid & 63;
  const int l = lane & 15, quad = lane >> 4;
  const int blk = blockIdx.x, bh = blockIdx.y;
  const uint16_t* FQh  = FQ  + (size_t)bh * NTOK * 64;
  const uint16_t* FVth = FVt + (size_t)bh * 288 * 64 * 32;
  const uint16_t* MQh  = MQ  + (size_t)bh * 256 * 64;
  const uint16_t* MVTh = MVT + (size_t)bh * 64 * 256;
  uint16_t* FOh = FO + (size_t)bh * NTOK * 64;

  // ---- hoisted loop-invariant operand fragments ----
  bf16x8 kb[4][2];   // MQ: wave w's 64 map-tokens, both k-halves
  #pragma unroll
  for (int jt = 0; jt < 4; ++jt) {
    const int j = w * 64 + jt * 16 + l;
    kb[jt][0] = *(const bf16x8*)(MQh + (size_t)j * 64 + quad * 8);
    kb[jt][1] = *(const bf16x8*)(MQh + (size_t)j * 64 + 32 + quad * 8);
  }
  bf16x8 avr[8];     // MVT: wave w's 16 d-rows, all 8 k-slices
  #pragma unroll
  for (int ks = 0; ks < 8; ++ks)
    avr[ks] = *(const bf16x8*)(MVTh + (size_t)(w * 16 + l) * 256 + ks * 32 + quad * 8);

  f32x4 numacc[4][4];
  #pragma unroll
  for (int a = 0; a < 4; ++a)
    #pragma unroll
    for (int b = 0; b < 4; ++b) { numacc[a][b].x = 0.f; numacc[a][b].y = 0.f; numacc[a][b].z = 0.f; numacc[a][b].w = 0.f; }
  float csum[4] = {0.f, 0.f, 0.f, 0.f};

  for (int t = 0; t < TPB; ++t) {
    const int it = blk * TPB + t;
    const int i0 = it * 32;

    // ---- QK phase: e_ij into Esh [i][j] and ETsh [j][i]
    bf16x8 qa[2][2];
    #pragma unroll
    for (int mt = 0; mt < 2; ++mt)
      #pragma unroll
      for (int kbi = 0; kbi < 2; ++kbi)
        qa[mt][kbi] = *(const bf16x8*)(FQh + (size_t)(i0 + mt * 16 + l) * 64 + kbi * 32 + quad * 8);

    float rsum[2][4] = {{0.f,0.f,0.f,0.f},{0.f,0.f,0.f,0.f}};
    #pragma unroll
    for (int jt = 0; jt < 4; ++jt) {
      const int j0 = w * 64 + jt * 16;
      #pragma unroll
      for (int mt = 0; mt < 2; ++mt) {
        f32x4 acc = {0.f, 0.f, 0.f, 0.f};
        acc = mfma16(qa[mt][0], kb[jt][0], acc);
        acc = mfma16(qa[mt][1], kb[jt][1], acc);
        union { uint16_t h[4]; uint2 u; } pk;
        #pragma unroll
        for (int r = 0; r < 4; ++r) {
          const float e = __expf(acc[r] * ATT_SCALE);
          rsum[mt][r] += e;
          csum[jt] += e;
          pk.h[r] = f2b(e);
          Esh[(mt * 16 + quad * 4 + r) * PJ + j0 + l] = pk.h[r];
        }
        *(uint2*)(ETsh + (size_t)(j0 + l) * PI + mt * 16 + quad * 4) = pk.u;
      }
    }
    #pragma unroll
    for (int mt = 0; mt < 2; ++mt)
      #pragma unroll
      for (int r = 0; r < 4; ++r) {
        float v = rsum[mt][r];
        v += __shfl_xor(v, 1); v += __shfl_xor(v, 2);
        v += __shfl_xor(v, 4); v += __shfl_xor(v, 8);
        if (l == 0) RS[w][mt * 16 + quad * 4 + r] = v;
      }
    __syncthreads();

    // ---- issue column-phase FVt loads; row phase below covers their latency
    bf16x8 av[4];
    #pragma unroll
    for (int mt = 0; mt < 4; ++mt)
      av[mt] = *(const bf16x8*)(FVth + ((size_t)it * 64 + mt * 16 + l) * 32 + quad * 8);

    // ---- row phase: feat_o^T[d][i] = MVT x E^T, normalized -> Osh
    {
      float rinv[2];
      #pragma unroll
      for (int nt = 0; nt < 2; ++nt) {
        const int i_ = nt * 16 + l;
        rinv[nt] = 1.f / (RS[0][i_] + RS[1][i_] + RS[2][i_] + RS[3][i_]);
      }
      f32x4 oacc[2];
      oacc[0].x=0.f;oacc[0].y=0.f;oacc[0].z=0.f;oacc[0].w=0.f;
      oacc[1]=oacc[0];
      #pragma unroll
      for (int ks = 0; ks < 8; ++ks) {
        #pragma unroll
        for (int nt = 0; nt < 2; ++nt) {
          const bf16x8 bv = *(const bf16x8*)(Esh + (size_t)(nt * 16 + l) * PJ + ks * 32 + quad * 8);
          oacc[nt] = mfma16(avr[ks], bv, oacc[nt]);
        }
      }
      #pragma unroll
      for (int nt = 0; nt < 2; ++nt) {
        union { uint16_t h[4]; uint2 u; } pk;
        #pragma unroll
        for (int r = 0; r < 4; ++r) pk.h[r] = f2b(oacc[nt][r] * rinv[nt]);
        *(uint2*)(Osh + (nt * 16 + l) * PO + w * 16 + quad * 4) = pk.u;
      }
    }

    // ---- column phase: NUM^T[d][j] += FVt-tile x E (regs across tiles)
    #pragma unroll
    for (int mt = 0; mt < 4; ++mt) {
      #pragma unroll
      for (int nt2 = 0; nt2 < 4; ++nt2) {
        const bf16x8 bv = *(const bf16x8*)(ETsh + (size_t)(w * 64 + nt2 * 16 + l) * PI + quad * 8);
        numacc[mt][nt2] = mfma16(av[mt], bv, numacc[mt][nt2]);
      }
    }
    __syncthreads();

    // ---- FO write: full 128-B line per token (8 thr x uint4)
    {
      const int ti = tid >> 3, c = tid & 7;
      *(uint4*)(FOh + (size_t)(i0 + ti) * 64 + c * 8) =
          *(const uint4*)(Osh + ti * PO + c * 8);
    }
  }

  // ---- flush partials: P[j][64d] rows are exactly one 128-B line each
  uint16_t* Pb = P + ((size_t)bh * NGRP + blk) * 256 * 64;
  #pragma unroll
  for (int mt = 0; mt < 4; ++mt)
    #pragma unroll
    for (int nt2 = 0; nt2 < 4; ++nt2) {
      const int j = w * 64 + nt2 * 16 + l;
      union { uint16_t h[4]; uint2 u; } pk;
      #pragma unroll
      for (int r = 0; r < 4; ++r) pk.h[r] = f2b(numacc[mt][nt2][r]);
      *(uint2*)(Pb + (size_t)j * 64 + mt * 16 + quad * 4) = pk.u;
    }
  uint16_t* CSb = CSp + ((size_t)bh * NGRP + blk) * 256;
  #pragma unroll
  for (int jt = 0; jt < 4; ++jt) {
    float v = csum[jt];
    v += __shfl_xor(v, 16); v += __shfl_xor(v, 32);
    if (quad == 0) CSb[w * 64 + jt * 16 + l] = f2b(v);
  }
}

// ---------------------------------------------------------------------------
// Epilogue: gemm1 (feat out proj) and reduce_map (P,CS -> MO), mergeable.
// Round-8: gemm1 output goes through LDS so stores are float4 / 256-B
// segments (was 64 scalar dword stores -> 64-B partial-line segments on the
// 151 MB fp32 output stream).
// ---------------------------------------------------------------------------
constexpr int PG = 260;  // gemm1 staging pitch (f32 words)

template<int DT>
DI void gemm1_dev(int gidx, const uint16_t* __restrict__ WfoP,
                  const uint16_t* __restrict__ FO, void* __restrict__ out,
                  float* __restrict__ Gsh)
{
  const int tid = threadIdx.x;
  const int w = tid >> 6, lane = tid & 63;
  const int l = lane & 15, quad = lane >> 4;
  const int n0 = (gidx % 36) * 256;
  const int o0 = ((gidx / 36) & 3) * 64;
  const int bb = gidx / 144;

  f32x4 acc[4][4];
  #pragma unroll
  for (int a = 0; a < 4; ++a)
    #pragma unroll
    for (int b = 0; b < 4; ++b) { acc[a][b].x = 0.f; acc[a][b].y = 0.f; acc[a][b].z = 0.f; acc[a][b].w = 0.f; }

  #pragma unroll
  for (int ks = 0; ks < 8; ++ks) {
    const int h2 = ks >> 1;
    const int doff = (ks & 1) * 32 + quad * 8;
    bf16x8 af[4];
    #pragma unroll
    for (int mt = 0; mt < 4; ++mt)
      af[mt] = *(const bf16x8*)(WfoP + (size_t)(o0 + mt * 16 + l) * 256 + ks * 32 + quad * 8);
    #pragma unroll
    for (int nt = 0; nt < 4; ++nt) {
      const int n = n0 + w * 64 + nt * 16 + l;
      const bf16x8 bv = *(const bf16x8*)(FO + ((size_t)(bb * 4 + h2) * NTOK + n) * 64 + doff);
      #pragma unroll
      for (int mt = 0; mt < 4; ++mt)
        acc[mt][nt] = mfma16(af[mt], bv, acc[mt][nt]);
    }
  }

  // ---- staged output: per mt-tile, assemble [16 o][256 n] in LDS, then
  // write float4 (fp32) / uint2 (bf16) with lane-consecutive addresses.
  #pragma unroll
  for (int mt = 0; mt < 4; ++mt) {
    if (mt) __syncthreads();
    #pragma unroll
    for (int nt = 0; nt < 4; ++nt)
      #pragma unroll
      for (int r = 0; r < 4; ++r)
        Gsh[(quad * 4 + r) * PG + w * 64 + nt * 16 + l] = acc[mt][nt][r];
    __syncthreads();
    const int row = tid >> 4, c = tid & 15;
    const size_t obase = ((size_t)bb * 256 + o0 + mt * 16 + row) * NTOK + n0;
    #pragma unroll
    for (int k = 0; k < 4; ++k) {
      const int nc = k * 64 + c * 4;
      const float* src = Gsh + row * PG + nc;
      if constexpr (DT) {
        union { uint16_t h[4]; uint2 u; } pk;
        #pragma unroll
        for (int q2 = 0; q2 < 4; ++q2) pk.h[q2] = f2b(src[q2]);
        *(uint2*)((uint16_t*)out + obase + nc) = pk.u;
      } else {
        *(float4*)((float*)out + obase + nc) = *(const float4*)src;
      }
    }
  }
}

DI void reduce_dev(int bid, const uint16_t* __restrict__ P,
                   const uint16_t* __restrict__ CSp, uint16_t* __restrict__ MO)
{
  const int idx = bid * 256 + threadIdx.x;   // 262144 total over 1024 blocks
  const int d = idx & 63;
  const int j = (idx >> 6) & 255;
  const int bh = idx >> 14;
  const size_t base = (size_t)bh * NGRP * 256 * 64;
  const size_t cb = (size_t)bh * NGRP * 256;
  float num = 0.f, cs = 0.f;
  #pragma unroll 6
  for (int g = 0; g < NGRP; ++g) {
    num += b2f(P[base + ((size_t)g * 256 + j) * 64 + d]);
    cs  += b2f(CSp[cb + (size_t)g * 256 + j]);
  }
  const float v = num / cs;
  const int b = bh >> 2, h = bh & 3;
  MO[((size_t)b * 256 + (d * 4 + h)) * 256 + j] = f2b(v);
}

__global__ __launch_bounds__(256) void epilogue_k(
    const uint16_t* WfoP, const uint16_t* FO, void* out,
    const uint16_t* P, const uint16_t* CSp, uint16_t* MO,
    const void* Wfqv, int mode)
{
  __shared__ __align__(16) float Gsh[16 * PG];
  const int bid = blockIdx.x;
  bool do_g1; int gidx;
  if (mode == 0)      { do_g1 = bid < 576; gidx = do_g1 ? bid : bid - 576; }
  else if (mode == 1) { do_g1 = true;  gidx = bid; }
  else                { do_g1 = false; gidx = bid; }
  if (do_g1) {
    const int fl = block_flag256((const uint32_t*)Wfqv);
    if (fl) gemm1_dev<1>(gidx, WfoP, FO, out, Gsh);
    else    gemm1_dev<0>(gidx, WfoP, FO, out, Gsh);
  } else {
    reduce_dev(gidx, P, CSp, MO);
  }
}

// ---------------------------------------------------------------------------
// map output projection (tiny)
// ---------------------------------------------------------------------------
template<int DT>
DI void map_out_body(const void* __restrict__ Wmo, const uint16_t* __restrict__ MO,
                     void* __restrict__ out)
{
  const int o = blockIdx.x, bb = blockIdx.y, m = threadIdx.x;
  float acc = 0.f;
  #pragma unroll 8
  for (int c = 0; c < 256; ++c)
    acc += ld1<DT>(Wmo, (size_t)o * 256 + c) *
           b2f(MO[((size_t)bb * 256 + c) * 256 + m]);
  const size_t MAP_OFS = (size_t)4 * 256 * NTOK;
  st1<DT>(out, MAP_OFS + ((size_t)bb * 256 + o) * 256 + m, acc);
}
__global__ __launch_bounds__(256) void map_out_k(
    const void* Wmo, const uint16_t* MO, void* out, const void* Wfqv)
{
  const int fl = block_flag256((const uint32_t*)Wfqv);
  if (fl) map_out_body<1>(Wmo, MO, out);
  else    map_out_body<0>(Wmo, MO, out);
}

extern "C" void kernel_launch(void* const* d_in, const int* in_sizes, int n_in,
                              void* d_out, int out_size, void* d_ws, size_t ws_size,
                              hipStream_t stream) {
  (void)in_sizes; (void)n_in; (void)out_size;
  const void* feat = d_in[0];
  const void* smap = d_in[1];
  const void* Wfqv = d_in[2];
  const void* Wmqv = d_in[3];
  const void* Wfo  = d_in[4];
  const void* Wmo  = d_in[5];
  char* ws = (char*)d_ws;

  const size_t BIG = (size_t)16 * 64 * NTOK * 2;   // 18,874,368 B
  const size_t SML = (size_t)16 * 256 * 64 * 2;    //    524,288 B
  const size_t FQ_OFF  = 0;                         // FO aliases FQ (token-major)
  const size_t FVT_OFF = FQ_OFF + BIG;
  const size_t MQ_OFF  = FVT_OFF + BIG;
  const size_t MVT_OFF = MQ_OFF + SML;
  const size_t MO_OFF  = MVT_OFF + SML;
  const size_t WQP_OFF = MO_OFF + (size_t)4 * 256 * 256 * 2;
  const size_t WFP_OFF = WQP_OFF + (size_t)512 * 256 * 2;
  const size_t CS_OFF  = WFP_OFF + (size_t)256 * 256 * 2;
  const size_t CS_SIZE = (size_t)16 * NGRP * 256 * 2;        //    393,216 B
  const size_t P_OFF   = CS_OFF + CS_SIZE;
  const size_t P_SIZE  = (size_t)16 * NGRP * 256 * 64 * 2;   // 25,165,824 B
  const size_t NEED    = P_OFF + P_SIZE;                      // ~65.7 MB

  uint16_t* FQ   = (uint16_t*)(ws + FQ_OFF);
  uint16_t* FVt  = (uint16_t*)(ws + FVT_OFF);
  uint16_t* MQ   = (uint16_t*)(ws + MQ_OFF);
  uint16_t* MVT  = (uint16_t*)(ws + MVT_OFF);
  uint16_t* MO   = (uint16_t*)(ws + MO_OFF);
  uint16_t* WqvP = (uint16_t*)(ws + WQP_OFF);
  uint16_t* WfoP = (uint16_t*)(ws + WFP_OFF);

  const bool p_in_ws = (ws_size >= NEED);
  // merged path: P,CS in workspace -> reduce_map concurrent with gemm1.
  // fallback: P,CS in d_out (25.6 MB <= 38.8 MB) -> reduce precedes gemm1.
  uint16_t* P   = p_in_ws ? (uint16_t*)(ws + P_OFF) : (uint16_t*)d_out;
  uint16_t* CSp = p_in_ws ? (uint16_t*)(ws + CS_OFF)
                          : (uint16_t*)((char*)d_out + P_SIZE);

  prep_map_k<<<dim3(2816), 256, 0, stream>>>(Wfqv, Wfo, Wmqv, smap,
                                             WqvP, WfoP, MQ, MVT);
  gemm0_mfma<<<dim3(144, 4), 256, 0, stream>>>(WqvP, feat, FQ, FVt, Wfqv);
  attn_mfma<<<dim3(NGRP, 16), 256, 0, stream>>>(FQ, FVt, MQ, MVT, FQ, P, CSp);
  if (p_in_ws) {
    epilogue_k<<<dim3(1600), 256, 0, stream>>>(WfoP, FQ, d_out, P, CSp, MO, Wfqv, 0);
  } else {
    epilogue_k<<<dim3(1024), 256, 0, stream>>>(WfoP, FQ, d_out, P, CSp, MO, Wfqv, 2);
    epilogue_k<<<dim3(576),  256, 0, stream>>>(WfoP, FQ, d_out, P, CSp, MO, Wfqv, 1);
  }
  map_out_k<<<dim3(256, 4), 256, 0, stream>>>(Wmo, MO, d_out, Wfqv);
}

// Round 9
// 286.437 us; speedup vs baseline: 1.0465x; 1.0099x over previous
//
#include <hip/hip_runtime.h>
#include <stdint.h>

#define DI static __device__ __forceinline__

constexpr int NTOK = 9216;   // 96*96 feat tokens per batch
constexpr float ATT_SCALE = 0.125f;

typedef short bf16x8 __attribute__((ext_vector_type(8)));
typedef float f32x4  __attribute__((ext_vector_type(4)));

DI f32x4 mfma16(bf16x8 a, bf16x8 b, f32x4 c) {
  return __builtin_amdgcn_mfma_f32_16x16x32_bf16(a, b, c, 0, 0, 0);
}

DI float b2f(uint16_t u) { union { uint32_t i; float f; } v; v.i = ((uint32_t)u) << 16; return v.f; }
DI uint16_t f2b(float f) {
  union { float f; uint32_t i; } v; v.f = f;
  uint32_t r = (v.i + 0x7fffu + ((v.i >> 16) & 1u)) >> 16;
  return (uint16_t)r;
}

// ---- dtype-generic element access (DT: 1 = bf16 storage, 0 = fp32 storage) --
template<int DT> DI float ld1(const void* p, size_t off) {
  if constexpr (DT) return b2f(((const uint16_t*)p)[off]);
  else              return ((const float*)p)[off];
}
template<int DT> DI void st1(void* p, size_t off, float v) {
  if constexpr (DT) ((uint16_t*)p)[off] = f2b(v);
  else              ((float*)p)[off] = v;
}

// ---------------------------------------------------------------------------
// Inline per-block dtype flag (low halves of Wfqv words 0..255; bf16-
// plausible magnitude count >= 128). Requires 256-thread blocks.
// ---------------------------------------------------------------------------
DI int block_flag256(const uint32_t* __restrict__ w) {
  const float b = b2f((uint16_t)(w[threadIdx.x & 255] & 0xffffu));
  const float ab = fabsf(b);
  return (__syncthreads_count((ab > 1e-4f && ab < 0.5f) ? 1 : 0) >= 128) ? 1 : 0;
}

// ---------------------------------------------------------------------------
// K1 merged: prep_w (blocks 0..767) || map_qv (blocks 768..1279).
// Round-9: map_qv computes 4 output channels per block, reusing each
// coalesced smap load for 4 FMAs (L2 traffic 512 -> 128 MB, blocks
// 2048 -> 512).
// ---------------------------------------------------------------------------
template<int DT>
DI void prep_w_dev(int r, const void* __restrict__ Wfqv, const void* __restrict__ Wfo,
                   uint16_t* __restrict__ WqvP, uint16_t* __restrict__ WfoP)
{
  const int c = threadIdx.x;
  if (r < 512) {
    const int sel = r >> 8, within = r & 255;
    const int h = within >> 6, d = within & 63;
    const int src = sel * 256 + d * 4 + h;
    WqvP[(size_t)r * 256 + c] = f2b(ld1<DT>(Wfqv, (size_t)src * 256 + c));
  } else {
    const int ro = r - 512;
    WfoP[(size_t)ro * 256 + c] =
        f2b(ld1<DT>(Wfo, (size_t)ro * 256 + (c & 63) * 4 + (c >> 6)));
  }
}

template<int DT>
DI void map_qv_dev4(int o4, int bb, const void* __restrict__ Wqv,
                    const void* __restrict__ smap,
                    uint16_t* __restrict__ MQ, uint16_t* __restrict__ MVT)
{
  const int m = threadIdx.x;
  const int o0 = o4 * 4;
  float acc[4] = {0.f, 0.f, 0.f, 0.f};
  #pragma unroll 4
  for (int c = 0; c < 256; ++c) {
    const float sv = ld1<DT>(smap, (size_t)bb * 65536 + (size_t)c * 256 + m);
    #pragma unroll
    for (int q = 0; q < 4; ++q)
      acc[q] += ld1<DT>(Wqv, (size_t)(o0 + q) * 256 + c) * sv;
  }
  #pragma unroll
  for (int q = 0; q < 4; ++q) {
    const int o = o0 + q;
    const int oc = o & 255;
    const int h = oc & 3, d = oc >> 2;
    if (o < 256) MQ[(((size_t)bb * 4 + h) * 256 + m) * 64 + d] = f2b(acc[q]);
    else         MVT[(((size_t)bb * 4 + h) * 64 + d) * 256 + m] = f2b(acc[q]);
  }
}

__global__ __launch_bounds__(256) void prep_map_k(
    const void* Wfqv, const void* Wfo, const void* Wmqv, const void* smap,
    uint16_t* WqvP, uint16_t* WfoP, uint16_t* MQ, uint16_t* MVT)
{
  const int fl = block_flag256((const uint32_t*)Wfqv);
  const int bid = blockIdx.x;
  if (bid < 768) {
    if (fl) prep_w_dev<1>(bid, Wfqv, Wfo, WqvP, WfoP);
    else    prep_w_dev<0>(bid, Wfqv, Wfo, WqvP, WfoP);
  } else {
    const int idx = bid - 768;          // 0..511
    const int o4 = idx & 127, bb = idx >> 7;
    if (fl) map_qv_dev4<1>(o4, bb, Wmqv, smap, MQ, MVT);
    else    map_qv_dev4<0>(o4, bb, Wmqv, smap, MQ, MVT);
  }
}

// ---------------------------------------------------------------------------
// GEMM0 (QV projection), MFMA. Grid (144 n-slabs, 4 batch), 256 thr.
// FROZEN at the R6/R8-measured version.
// ---------------------------------------------------------------------------
constexpr int P0 = 280;   // gemm0 LDS token-row pitch (elems)

template<int DT>
DI void gemm0_body(uint16_t* Xs, const uint16_t* __restrict__ WqvP,
                   const void* __restrict__ X,
                   uint16_t* __restrict__ FQ, uint16_t* __restrict__ FVt)
{
  const int tid = threadIdx.x;
  const int w = tid >> 6, lane = tid & 63;
  const int l = lane & 15, quad = lane >> 4;
  const int n0 = blockIdx.x * 64;
  const int bb = blockIdx.y;
  const size_t bh = (size_t)bb * 4 + w;    // wave w handles head w

  {
    const int nb = (tid & 31) * 2;
    const int kg = tid >> 5;
    #pragma unroll
    for (int pass = 0; pass < 4; ++pass) {
      const int k0 = pass * 64 + kg * 8;
      union { uint16_t h[8]; uint4 u; } pk0, pk1;
      #pragma unroll
      for (int j = 0; j < 8; ++j) {
        const size_t g = ((size_t)bb * 256 + k0 + j) * NTOK + n0 + nb;
        if constexpr (DT) {
          const uint32_t v = *(const uint32_t*)((const uint16_t*)X + g);
          pk0.h[j] = (uint16_t)(v & 0xffffu);
          pk1.h[j] = (uint16_t)(v >> 16);
        } else {
          const float2 v = *(const float2*)((const float*)X + g);
          pk0.h[j] = f2b(v.x);
          pk1.h[j] = f2b(v.y);
        }
      }
      *(uint4*)(Xs + (size_t)(nb + 0) * P0 + k0) = pk0.u;
      *(uint4*)(Xs + (size_t)(nb + 1) * P0 + k0) = pk1.u;
    }
  }
  __syncthreads();

  f32x4 acc[8][4];
  #pragma unroll
  for (int a = 0; a < 8; ++a)
    #pragma unroll
    for (int b = 0; b < 4; ++b) { acc[a][b].x = 0.f; acc[a][b].y = 0.f; acc[a][b].z = 0.f; acc[a][b].w = 0.f; }

  for (int ks = 0; ks < 8; ++ks) {
    bf16x8 af[8];
    #pragma unroll
    for (int mt = 0; mt < 8; ++mt) {
      const int arow = (mt >> 2) * 256 + w * 64 + (mt & 3) * 16 + l;
      af[mt] = *(const bf16x8*)(WqvP + (size_t)arow * 256 + ks * 32 + quad * 8);
    }
    #pragma unroll
    for (int nt = 0; nt < 4; ++nt) {
      const bf16x8 bv = *(const bf16x8*)(Xs + (size_t)(nt * 16 + l) * P0 + ks * 32 + quad * 8);
      #pragma unroll
      for (int mt = 0; mt < 8; ++mt)
        acc[mt][nt] = mfma16(af[mt], bv, acc[mt][nt]);
    }
  }
  #pragma unroll
  for (int mt = 0; mt < 8; ++mt)
    #pragma unroll
    for (int nt = 0; nt < 4; ++nt) {
      const int n = n0 + nt * 16 + l;
      if (mt < 4) {
        union { uint16_t h[4]; uint2 u; } pk;
        #pragma unroll
        for (int r = 0; r < 4; ++r) pk.h[r] = f2b(acc[mt][nt][r]);
        *(uint2*)(FQ + (bh * NTOK + n) * 64 + mt * 16 + quad * 4) = pk.u;
      } else {
        const int itile = n >> 5, io = n & 31;
        #pragma unroll
        for (int r = 0; r < 4; ++r)
          FVt[(((size_t)bh * 288 + itile) * 64 + (mt - 4) * 16 + quad * 4 + r) * 32 + io] =
              f2b(acc[mt][nt][r]);
      }
    }
}
__global__ __launch_bounds__(256) void gemm0_mfma(
    const uint16_t* WqvP, const void* X, uint16_t* FQ, uint16_t* FVt,
    const void* Wfqv)
{
  __shared__ __align__(16) uint16_t Xs[64 * P0];
  const int fl = block_flag256((const uint32_t*)Wfqv);
  if (fl) gemm0_body<1>(Xs, WqvP, X, FQ, FVt);
  else    gemm0_body<0>(Xs, WqvP, X, FQ, FVt);
}

// ---------------------------------------------------------------------------
// Fused bidirectional attention, MFMA 16x16x32 bf16. Grid (48, 16).
// FROZEN at the R7/R8-measured configuration (86.4 us, occ 29%).
// ---------------------------------------------------------------------------
constexpr int PJ = 280;  // E[i][j] row pitch (560B rows, 16B-aligned)
constexpr int PI = 40;   // ET[j][i] row pitch (80B rows, 16B-aligned)
constexpr int PO = 72;   // Osh row pitch (144 B: 16B-aligned, bank-spread)
constexpr int NGRP = 48; // partial groups (= blocks) per bh
constexpr int TPB = 6;   // i-tiles (of 32 tokens) per block = 288/NGRP

__global__ __launch_bounds__(256, 3) void attn_mfma(
    const uint16_t* __restrict__ FQ, const uint16_t* __restrict__ FVt,
    const uint16_t* __restrict__ MQ, const uint16_t* __restrict__ MVT,
    uint16_t* __restrict__ FO, uint16_t* __restrict__ P,
    uint16_t* __restrict__ CSp)
{
  __shared__ __align__(16) uint16_t Esh[32 * PJ];    // [i][j]
  __shared__ __align__(16) uint16_t ETsh[256 * PI];  // [j][i]
  __shared__ __align__(16) uint16_t Osh[32 * PO];    // [i][d] out-staging
  __shared__ float RS[4][32];
  const int tid = threadIdx.x;
  const int w = tid >> 6;
  const int lane = tid & 63;
  const int l = lane & 15, quad = lane >> 4;
  const int blk = blockIdx.x, bh = blockIdx.y;
  const uint16_t* FQh  = FQ  + (size_t)bh * NTOK * 64;
  const uint16_t* FVth = FVt + (size_t)bh * 288 * 64 * 32;
  const uint16_t* MQh  = MQ  + (size_t)bh * 256 * 64;
  const uint16_t* MVTh = MVT + (size_t)bh * 64 * 256;
  uint16_t* FOh = FO + (size_t)bh * NTOK * 64;

  // ---- hoisted loop-invariant operand fragments ----
  bf16x8 kb[4][2];   // MQ: wave w's 64 map-tokens, both k-halves
  #pragma unroll
  for (int jt = 0; jt < 4; ++jt) {
    const int j = w * 64 + jt * 16 + l;
    kb[jt][0] = *(const bf16x8*)(MQh + (size_t)j * 64 + quad * 8);
    kb[jt][1] = *(const bf16x8*)(MQh + (size_t)j * 64 + 32 + quad * 8);
  }
  bf16x8 avr[8];     // MVT: wave w's 16 d-rows, all 8 k-slices
  #pragma unroll
  for (int ks = 0; ks < 8; ++ks)
    avr[ks] = *(const bf16x8*)(MVTh + (size_t)(w * 16 + l) * 256 + ks * 32 + quad * 8);

  f32x4 numacc[4][4];
  #pragma unroll
  for (int a = 0; a < 4; ++a)
    #pragma unroll
    for (int b = 0; b < 4; ++b) { numacc[a][b].x = 0.f; numacc[a][b].y = 0.f; numacc[a][b].z = 0.f; numacc[a][b].w = 0.f; }
  float csum[4] = {0.f, 0.f, 0.f, 0.f};

  for (int t = 0; t < TPB; ++t) {
    const int it = blk * TPB + t;
    const int i0 = it * 32;

    // ---- QK phase: e_ij into Esh [i][j] and ETsh [j][i]
    bf16x8 qa[2][2];
    #pragma unroll
    for (int mt = 0; mt < 2; ++mt)
      #pragma unroll
      for (int kbi = 0; kbi < 2; ++kbi)
        qa[mt][kbi] = *(const bf16x8*)(FQh + (size_t)(i0 + mt * 16 + l) * 64 + kbi * 32 + quad * 8);

    float rsum[2][4] = {{0.f,0.f,0.f,0.f},{0.f,0.f,0.f,0.f}};
    #pragma unroll
    for (int jt = 0; jt < 4; ++jt) {
      const int j0 = w * 64 + jt * 16;
      #pragma unroll
      for (int mt = 0; mt < 2; ++mt) {
        f32x4 acc = {0.f, 0.f, 0.f, 0.f};
        acc = mfma16(qa[mt][0], kb[jt][0], acc);
        acc = mfma16(qa[mt][1], kb[jt][1], acc);
        union { uint16_t h[4]; uint2 u; } pk;
        #pragma unroll
        for (int r = 0; r < 4; ++r) {
          const float e = __expf(acc[r] * ATT_SCALE);
          rsum[mt][r] += e;
          csum[jt] += e;
          pk.h[r] = f2b(e);
          Esh[(mt * 16 + quad * 4 + r) * PJ + j0 + l] = pk.h[r];
        }
        *(uint2*)(ETsh + (size_t)(j0 + l) * PI + mt * 16 + quad * 4) = pk.u;
      }
    }
    #pragma unroll
    for (int mt = 0; mt < 2; ++mt)
      #pragma unroll
      for (int r = 0; r < 4; ++r) {
        float v = rsum[mt][r];
        v += __shfl_xor(v, 1); v += __shfl_xor(v, 2);
        v += __shfl_xor(v, 4); v += __shfl_xor(v, 8);
        if (l == 0) RS[w][mt * 16 + quad * 4 + r] = v;
      }
    __syncthreads();

    // ---- issue column-phase FVt loads; row phase below covers their latency
    bf16x8 av[4];
    #pragma unroll
    for (int mt = 0; mt < 4; ++mt)
      av[mt] = *(const bf16x8*)(FVth + ((size_t)it * 64 + mt * 16 + l) * 32 + quad * 8);

    // ---- row phase: feat_o^T[d][i] = MVT x E^T, normalized -> Osh
    {
      float rinv[2];
      #pragma unroll
      for (int nt = 0; nt < 2; ++nt) {
        const int i_ = nt * 16 + l;
        rinv[nt] = 1.f / (RS[0][i_] + RS[1][i_] + RS[2][i_] + RS[3][i_]);
      }
      f32x4 oacc[2];
      oacc[0].x=0.f;oacc[0].y=0.f;oacc[0].z=0.f;oacc[0].w=0.f;
      oacc[1]=oacc[0];
      #pragma unroll
      for (int ks = 0; ks < 8; ++ks) {
        #pragma unroll
        for (int nt = 0; nt < 2; ++nt) {
          const bf16x8 bv = *(const bf16x8*)(Esh + (size_t)(nt * 16 + l) * PJ + ks * 32 + quad * 8);
          oacc[nt] = mfma16(avr[ks], bv, oacc[nt]);
        }
      }
      #pragma unroll
      for (int nt = 0; nt < 2; ++nt) {
        union { uint16_t h[4]; uint2 u; } pk;
        #pragma unroll
        for (int r = 0; r < 4; ++r) pk.h[r] = f2b(oacc[nt][r] * rinv[nt]);
        *(uint2*)(Osh + (nt * 16 + l) * PO + w * 16 + quad * 4) = pk.u;
      }
    }

    // ---- column phase: NUM^T[d][j] += FVt-tile x E (regs across tiles)
    #pragma unroll
    for (int mt = 0; mt < 4; ++mt) {
      #pragma unroll
      for (int nt2 = 0; nt2 < 4; ++nt2) {
        const bf16x8 bv = *(const bf16x8*)(ETsh + (size_t)(w * 64 + nt2 * 16 + l) * PI + quad * 8);
        numacc[mt][nt2] = mfma16(av[mt], bv, numacc[mt][nt2]);
      }
    }
    __syncthreads();

    // ---- FO write: full 128-B line per token (8 thr x uint4)
    {
      const int ti = tid >> 3, c = tid & 7;
      *(uint4*)(FOh + (size_t)(i0 + ti) * 64 + c * 8) =
          *(const uint4*)(Osh + ti * PO + c * 8);
    }
  }

  // ---- flush partials: P[j][64d] rows are exactly one 128-B line each
  uint16_t* Pb = P + ((size_t)bh * NGRP + blk) * 256 * 64;
  #pragma unroll
  for (int mt = 0; mt < 4; ++mt)
    #pragma unroll
    for (int nt2 = 0; nt2 < 4; ++nt2) {
      const int j = w * 64 + nt2 * 16 + l;
      union { uint16_t h[4]; uint2 u; } pk;
      #pragma unroll
      for (int r = 0; r < 4; ++r) pk.h[r] = f2b(numacc[mt][nt2][r]);
      *(uint2*)(Pb + (size_t)j * 64 + mt * 16 + quad * 4) = pk.u;
    }
  uint16_t* CSb = CSp + ((size_t)bh * NGRP + blk) * 256;
  #pragma unroll
  for (int jt = 0; jt < 4; ++jt) {
    float v = csum[jt];
    v += __shfl_xor(v, 16); v += __shfl_xor(v, 32);
    if (quad == 0) CSb[w * 64 + jt * 16 + l] = f2b(v);
  }
}

// ---------------------------------------------------------------------------
// Epilogue: gemm1 (feat out proj) and reduce_map (P,CS -> MO), mergeable.
// gemm1 output staged through LDS (float4 / 256-B segment stores).
// ---------------------------------------------------------------------------
constexpr int PG = 260;  // gemm1 staging pitch (f32 words)

template<int DT>
DI void gemm1_dev(int gidx, const uint16_t* __restrict__ WfoP,
                  const uint16_t* __restrict__ FO, void* __restrict__ out,
                  float* __restrict__ Gsh)
{
  const int tid = threadIdx.x;
  const int w = tid >> 6, lane = tid & 63;
  const int l = lane & 15, quad = lane >> 4;
  const int n0 = (gidx % 36) * 256;
  const int o0 = ((gidx / 36) & 3) * 64;
  const int bb = gidx / 144;

  f32x4 acc[4][4];
  #pragma unroll
  for (int a = 0; a < 4; ++a)
    #pragma unroll
    for (int b = 0; b < 4; ++b) { acc[a][b].x = 0.f; acc[a][b].y = 0.f; acc[a][b].z = 0.f; acc[a][b].w = 0.f; }

  #pragma unroll
  for (int ks = 0; ks < 8; ++ks) {
    const int h2 = ks >> 1;
    const int doff = (ks & 1) * 32 + quad * 8;
    bf16x8 af[4];
    #pragma unroll
    for (int mt = 0; mt < 4; ++mt)
      af[mt] = *(const bf16x8*)(WfoP + (size_t)(o0 + mt * 16 + l) * 256 + ks * 32 + quad * 8);
    #pragma unroll
    for (int nt = 0; nt < 4; ++nt) {
      const int n = n0 + w * 64 + nt * 16 + l;
      const bf16x8 bv = *(const bf16x8*)(FO + ((size_t)(bb * 4 + h2) * NTOK + n) * 64 + doff);
      #pragma unroll
      for (int mt = 0; mt < 4; ++mt)
        acc[mt][nt] = mfma16(af[mt], bv, acc[mt][nt]);
    }
  }

  #pragma unroll
  for (int mt = 0; mt < 4; ++mt) {
    if (mt) __syncthreads();
    #pragma unroll
    for (int nt = 0; nt < 4; ++nt)
      #pragma unroll
      for (int r = 0; r < 4; ++r)
        Gsh[(quad * 4 + r) * PG + w * 64 + nt * 16 + l] = acc[mt][nt][r];
    __syncthreads();
    const int row = tid >> 4, c = tid & 15;
    const size_t obase = ((size_t)bb * 256 + o0 + mt * 16 + row) * NTOK + n0;
    #pragma unroll
    for (int k = 0; k < 4; ++k) {
      const int nc = k * 64 + c * 4;
      const float* src = Gsh + row * PG + nc;
      if constexpr (DT) {
        union { uint16_t h[4]; uint2 u; } pk;
        #pragma unroll
        for (int q2 = 0; q2 < 4; ++q2) pk.h[q2] = f2b(src[q2]);
        *(uint2*)((uint16_t*)out + obase + nc) = pk.u;
      } else {
        *(float4*)((float*)out + obase + nc) = *(const float4*)src;
      }
    }
  }
}

DI void reduce_dev(int bid, const uint16_t* __restrict__ P,
                   const uint16_t* __restrict__ CSp, uint16_t* __restrict__ MO)
{
  const int idx = bid * 256 + threadIdx.x;   // 262144 total over 1024 blocks
  const int d = idx & 63;
  const int j = (idx >> 6) & 255;
  const int bh = idx >> 14;
  const size_t base = (size_t)bh * NGRP * 256 * 64;
  const size_t cb = (size_t)bh * NGRP * 256;
  float num = 0.f, cs = 0.f;
  #pragma unroll 6
  for (int g = 0; g < NGRP; ++g) {
    num += b2f(P[base + ((size_t)g * 256 + j) * 64 + d]);
    cs  += b2f(CSp[cb + (size_t)g * 256 + j]);
  }
  const float v = num / cs;
  const int b = bh >> 2, h = bh & 3;
  MO[((size_t)b * 256 + (d * 4 + h)) * 256 + j] = f2b(v);
}

__global__ __launch_bounds__(256) void epilogue_k(
    const uint16_t* WfoP, const uint16_t* FO, void* out,
    const uint16_t* P, const uint16_t* CSp, uint16_t* MO,
    const void* Wfqv, int mode)
{
  __shared__ __align__(16) float Gsh[16 * PG];
  const int bid = blockIdx.x;
  bool do_g1; int gidx;
  if (mode == 0)      { do_g1 = bid < 576; gidx = do_g1 ? bid : bid - 576; }
  else if (mode == 1) { do_g1 = true;  gidx = bid; }
  else                { do_g1 = false; gidx = bid; }
  if (do_g1) {
    const int fl = block_flag256((const uint32_t*)Wfqv);
    if (fl) gemm1_dev<1>(gidx, WfoP, FO, out, Gsh);
    else    gemm1_dev<0>(gidx, WfoP, FO, out, Gsh);
  } else {
    reduce_dev(gidx, P, CSp, MO);
  }
}

// ---------------------------------------------------------------------------
// map output projection: 4 output channels per block (L2 traffic /4).
// Grid (64, 4).
// ---------------------------------------------------------------------------
template<int DT>
DI void map_out_body4(const void* __restrict__ Wmo, const uint16_t* __restrict__ MO,
                      void* __restrict__ out)
{
  const int o0 = blockIdx.x * 4, bb = blockIdx.y, m = threadIdx.x;
  float acc[4] = {0.f, 0.f, 0.f, 0.f};
  #pragma unroll 4
  for (int c = 0; c < 256; ++c) {
    const float mv = b2f(MO[((size_t)bb * 256 + c) * 256 + m]);
    #pragma unroll
    for (int q = 0; q < 4; ++q)
      acc[q] += ld1<DT>(Wmo, (size_t)(o0 + q) * 256 + c) * mv;
  }
  const size_t MAP_OFS = (size_t)4 * 256 * NTOK;
  #pragma unroll
  for (int q = 0; q < 4; ++q)
    st1<DT>(out, MAP_OFS + ((size_t)bb * 256 + o0 + q) * 256 + m, acc[q]);
}
__global__ __launch_bounds__(256) void map_out_k(
    const void* Wmo, const uint16_t* MO, void* out, const void* Wfqv)
{
  const int fl = block_flag256((const uint32_t*)Wfqv);
  if (fl) map_out_body4<1>(Wmo, MO, out);
  else    map_out_body4<0>(Wmo, MO, out);
}

extern "C" void kernel_launch(void* const* d_in, const int* in_sizes, int n_in,
                              void* d_out, int out_size, void* d_ws, size_t ws_size,
                              hipStream_t stream) {
  (void)in_sizes; (void)n_in; (void)out_size;
  const void* feat = d_in[0];
  const void* smap = d_in[1];
  const void* Wfqv = d_in[2];
  const void* Wmqv = d_in[3];
  const void* Wfo  = d_in[4];
  const void* Wmo  = d_in[5];
  char* ws = (char*)d_ws;

  const size_t BIG = (size_t)16 * 64 * NTOK * 2;   // 18,874,368 B
  const size_t SML = (size_t)16 * 256 * 64 * 2;    //    524,288 B
  const size_t FQ_OFF  = 0;                         // FO aliases FQ (token-major)
  const size_t FVT_OFF = FQ_OFF + BIG;
  const size_t MQ_OFF  = FVT_OFF + BIG;
  const size_t MVT_OFF = MQ_OFF + SML;
  const size_t MO_OFF  = MVT_OFF + SML;
  const size_t WQP_OFF = MO_OFF + (size_t)4 * 256 * 256 * 2;
  const size_t WFP_OFF = WQP_OFF + (size_t)512 * 256 * 2;
  const size_t CS_OFF  = WFP_OFF + (size_t)256 * 256 * 2;
  const size_t CS_SIZE = (size_t)16 * NGRP * 256 * 2;        //    393,216 B
  const size_t P_OFF   = CS_OFF + CS_SIZE;
  const size_t P_SIZE  = (size_t)16 * NGRP * 256 * 64 * 2;   // 25,165,824 B
  const size_t NEED    = P_OFF + P_SIZE;                      // ~65.7 MB

  uint16_t* FQ   = (uint16_t*)(ws + FQ_OFF);
  uint16_t* FVt  = (uint16_t*)(ws + FVT_OFF);
  uint16_t* MQ   = (uint16_t*)(ws + MQ_OFF);
  uint16_t* MVT  = (uint16_t*)(ws + MVT_OFF);
  uint16_t* MO   = (uint16_t*)(ws + MO_OFF);
  uint16_t* WqvP = (uint16_t*)(ws + WQP_OFF);
  uint16_t* WfoP = (uint16_t*)(ws + WFP_OFF);

  const bool p_in_ws = (ws_size >= NEED);
  uint16_t* P   = p_in_ws ? (uint16_t*)(ws + P_OFF) : (uint16_t*)d_out;
  uint16_t* CSp = p_in_ws ? (uint16_t*)(ws + CS_OFF)
                          : (uint16_t*)((char*)d_out + P_SIZE);

  prep_map_k<<<dim3(1280), 256, 0, stream>>>(Wfqv, Wfo, Wmqv, smap,
                                             WqvP, WfoP, MQ, MVT);
  gemm0_mfma<<<dim3(144, 4), 256, 0, stream>>>(WqvP, feat, FQ, FVt, Wfqv);
  attn_mfma<<<dim3(NGRP, 16), 256, 0, stream>>>(FQ, FVt, MQ, MVT, FQ, P, CSp);
  if (p_in_ws) {
    epilogue_k<<<dim3(1600), 256, 0, stream>>>(WfoP, FQ, d_out, P, CSp, MO, Wfqv, 0);
  } else {
    epilogue_k<<<dim3(1024), 256, 0, stream>>>(WfoP, FQ, d_out, P, CSp, MO, Wfqv, 2);
    epilogue_k<<<dim3(576),  256, 0, stream>>>(WfoP, FQ, d_out, P, CSp, MO, Wfqv, 1);
  }
  map_out_k<<<dim3(64, 4), 256, 0, stream>>>(Wmo, MO, d_out, Wfqv);
}